// Round 6
// baseline (17.991 us; speedup 1.0000x reference)
//
#include <hip/hip_runtime.h>

#define T_LEN   2097152
#define CHUNK   8
#define BLOCK   256
#define NBLK    (T_LEN / (CHUNK * BLOCK))   // 1024
#define NWAVE   (BLOCK / 64)                // 4
#define FINAL_PER (NBLK / 256)              // 4

#define LOG2E 1.44269504088896340736f
#define LN2   0.69314718055994530942f

#if __has_builtin(__builtin_amdgcn_exp2f)
__device__ __forceinline__ float fexp2(float x) { return __builtin_amdgcn_exp2f(x); }
#else
__device__ __forceinline__ float fexp2(float x) { return exp2f(x); }
#endif
#if __has_builtin(__builtin_amdgcn_logf)
__device__ __forceinline__ float flog2(float x) { return __builtin_amdgcn_logf(x); }
#else
__device__ __forceinline__ float flog2(float x) { return log2f(x); }
#endif

// XOR swizzle: spreads 64B-strided reads across all 8 LDS bank-quads.
// Bijective (XORs addr bits 4-6 with a function of bits 6-8); preserves 16B
// alignment. Read pattern lane*64+k*16 verified conflict-free; writes <=2-way
// (free per m136).
__device__ __forceinline__ int SWZ(int r) { return r ^ (((r >> 6) & 7) << 4); }

// Exact power-of-two renorm: scale so max entry lands in [1,2). Scale is a pure
// power of 2 -> bit-exact, no rounding.
__device__ __forceinline__ void renorm4(float& a, float& b, float& c, float& d, int& e2) {
    float mx = fmaxf(fmaxf(a, b), fmaxf(c, d));
    int ex = (__float_as_int(mx) >> 23) & 0xff;
    float s = __int_as_float((254 - ex) << 23);          // 2^(127-ex)
    a *= s; b *= s; c *= s; d *= s;
    e2 += ex - 127;
}
__device__ __forceinline__ void renorm1(float& a, int& e2) {
    int ex = (__float_as_int(a) >> 23) & 0xff;
    float s = __int_as_float((254 - ex) << 23);
    a *= s;
    e2 += ex - 127;
}

// Ordered 64-lane butterfly over (2x2 mantissa, exp2 int, gold float).
// Linear matmul = 8 FMA, exponents add. Renorm only every 2 stages: inputs
// normalized to [1,2) grow <= 2^7 between renorms -> no overflow possible.
__device__ __forceinline__ void wave_reduce_lin(float& Pa, float& Pb, float& Pc, float& Pd,
                                                int& e2, float& g, int lane) {
    #pragma unroll
    for (int s = 0; s < 6; ++s) {
        const int m = 1 << s;
        float Oa = __shfl_xor(Pa, m), Ob = __shfl_xor(Pb, m);
        float Oc = __shfl_xor(Pc, m), Od = __shfl_xor(Pd, m);
        int   Oe = __shfl_xor(e2, m);
        g += __shfl_xor(g, m);
        const bool hi = (lane & m) != 0;                 // my segment comes AFTER partner's
        float Xa = hi?Oa:Pa, Xb = hi?Ob:Pb, Xc = hi?Oc:Pc, Xd = hi?Od:Pd;
        float Ya = hi?Pa:Oa, Yb = hi?Pb:Ob, Yc = hi?Pc:Oc, Yd = hi?Pd:Od;
        Pa = Xa*Ya + Xb*Yc;
        Pb = Xa*Yb + Xb*Yd;
        Pc = Xc*Ya + Xd*Yc;
        Pd = Xc*Yb + Xd*Yd;
        e2 += Oe;
        if (s & 1) renorm4(Pa, Pb, Pc, Pd, e2);
    }
}

__global__ __launch_bounds__(BLOCK) void crf_partial(
    const float* __restrict__ em,      // [T,2]
    const int*   __restrict__ label,   // [T]
    const int*   __restrict__ wst,     // [T] in 0..2
    const int*   __restrict__ pst,     // [T] in 0..19
    const float* __restrict__ w2w,     // [2,2,2]
    const float* __restrict__ pos,     // [19,2,2]
    float* __restrict__ outP,          // [NBLK,4] mantissas in [1,2)
    int*   __restrict__ outE,          // [NBLK]   exp2
    float* __restrict__ outG)          // [NBLK]   gold partials (natural log)
{
    __shared__ float4 combExp[60];     // exp(w2w_sub[w] + pos_sub[p]), row-major 2x2
    __shared__ __align__(16) char emS[NWAVE * 4096];   // per-wave 1024 floats (LOG2E-scaled)
    __shared__ __align__(16) char idxS[NWAVE * 2048];  // per-wave 512 packed ints
    __shared__ float4 wPs[NWAVE];
    __shared__ int    wEs[NWAVE];
    __shared__ float  wGs[NWAVE];

    const int tid  = threadIdx.x;
    const int wid  = tid >> 6;
    const int lane = tid & 63;

    if (tid < 60) {
        const int w = tid / 20, p = tid % 20;
        float v0 = 0.f, v1 = 0.f, v2 = 0.f, v3 = 0.f;
        if (w < 2)  { v0 += w2w[w*4+0]; v1 += w2w[w*4+1]; v2 += w2w[w*4+2]; v3 += w2w[w*4+3]; }
        if (p < 19) { v0 += pos[p*4+0]; v1 += pos[p*4+1]; v2 += pos[p*4+2]; v3 += pos[p*4+3]; }
        combExp[tid] = make_float4(fexp2(v0 * LOG2E), fexp2(v1 * LOG2E),
                                   fexp2(v2 * LOG2E), fexp2(v3 * LOG2E));
    }

    // ---- wave-cooperative coalesced staging (stride-16B global loads) ----
    const size_t wstart = (size_t)blockIdx.x * (BLOCK * CHUNK) + (size_t)wid * (64 * CHUNK);
    char* emW  = emS  + wid * 4096;
    char* idxW = idxS + wid * 2048;

    {   // em: 1024 floats per wave, scaled by LOG2E at stage time
        const float4* emg = (const float4*)(em + 2 * wstart);
        #pragma unroll
        for (int j = 0; j < 4; ++j) {
            float4 v = emg[j * 64 + lane];
            v.x *= LOG2E; v.y *= LOG2E; v.z *= LOG2E; v.w *= LOG2E;
            const int rel = j * 1024 + lane * 16;
            *(float4*)(emW + SWZ(rel)) = v;
        }
        // ints: pack (label<<11 | w*20+p) -> one array, 512 ints per wave
        const int4* lg = (const int4*)(label + wstart);
        const int4* wg = (const int4*)(wst   + wstart);
        const int4* pg = (const int4*)(pst   + wstart);
        #pragma unroll
        for (int j = 0; j < 2; ++j) {
            int4 lv = lg[j * 64 + lane];
            int4 wv = wg[j * 64 + lane];
            int4 pv = pg[j * 64 + lane];
            int4 x;
            x.x = (lv.x << 11) | (wv.x * 20 + pv.x);
            x.y = (lv.y << 11) | (wv.y * 20 + pv.y);
            x.z = (lv.z << 11) | (wv.z * 20 + pv.z);
            x.w = (lv.w << 11) | (wv.w * 20 + pv.w);
            const int rel = j * 1024 + lane * 16;
            *(int4*)(idxW + SWZ(rel)) = x;
        }
    }

    // One barrier covers combExp AND all staging writes (waits lgkmcnt(0)).
    __syncthreads();

    const size_t t0 = wstart + (size_t)lane * CHUNK;
    // prev label: lanes>0 read the previous lane's last packed element from LDS.
    int prev;
    if (lane == 0) prev = (t0 == 0) ? 0 : (label[t0 - 1] & 1);
    else           prev = (*(const int*)(idxW + SWZ(lane * 32 - 4))) >> 11;

    // ---- linear-domain fold over this lane's 8 steps ----
    const int relE = lane * 64;   // 16 floats
    const int relI = lane * 32;   // 8 packed ints

    float Pa, Pb, Pc, Pd;
    int   e2 = 0;
    float gEm  = 0.f;      // emission sum, log2-scaled domain
    float gLin = 1.f;      // gold transition product (linear) with exponent eg
    int   eg   = 0;

#define STEP(e0v, e1v, xp)                                                 \
    {                                                                      \
        const float e0 = (e0v), e1 = (e1v);                                \
        const int   xv = (xp);                                             \
        const float f0 = fexp2(e0);                                        \
        const float f1 = fexp2(e1);                                        \
        const float4 X = combExp[xv & 2047];                               \
        const int l = xv >> 11;                                            \
        gEm += l ? e1 : e0;                                                \
        gLin *= prev ? (l ? X.w : X.z) : (l ? X.y : X.x);                  \
        prev = l;                                                          \
        float na = (Pa*X.x + Pb*X.z) * f0;                                 \
        float nb = (Pa*X.y + Pb*X.w) * f1;                                 \
        float nc = (Pc*X.x + Pd*X.z) * f0;                                 \
        float nd = (Pc*X.y + Pd*X.w) * f1;                                 \
        Pa = na; Pb = nb; Pc = nc; Pd = nd;                                \
    }

    {   // group 0: steps 0..3 (step 0 initializes P = M[t0])
        float4 Ea = *(const float4*)(emW + SWZ(relE +  0));
        float4 Eb = *(const float4*)(emW + SWZ(relE + 16));
        int4   Xi = *(const int4*)(idxW + SWZ(relI));
        {
            const float f0 = fexp2(Ea.x), f1 = fexp2(Ea.y);
            const float4 X = combExp[Xi.x & 2047];
            const int l = Xi.x >> 11;
            gEm += l ? Ea.y : Ea.x;
            gLin *= prev ? (l ? X.w : X.z) : (l ? X.y : X.x);
            prev = l;
            Pa = X.x * f0;  Pb = X.y * f1;
            Pc = X.z * f0;  Pd = X.w * f1;
        }
        STEP(Ea.z, Ea.w, Xi.y)
        STEP(Eb.x, Eb.y, Xi.z)
        STEP(Eb.z, Eb.w, Xi.w)
        renorm4(Pa, Pb, Pc, Pd, e2);
        renorm1(gLin, eg);
    }
    {   // group 1: steps 4..7
        float4 Ea = *(const float4*)(emW + SWZ(relE + 32));
        float4 Eb = *(const float4*)(emW + SWZ(relE + 48));
        int4   Xi = *(const int4*)(idxW + SWZ(relI + 16));
        STEP(Ea.x, Ea.y, Xi.x)
        STEP(Ea.z, Ea.w, Xi.y)
        STEP(Eb.x, Eb.y, Xi.z)
        STEP(Eb.z, Eb.w, Xi.w)
        renorm4(Pa, Pb, Pc, Pd, e2);
    }
#undef STEP

    // gold partial to one natural-log scalar (the only per-thread log2)
    float g = (gEm + (float)eg + flog2(gLin)) * LN2;

    // ---- ordered reductions (fixed order -> deterministic) ----
    wave_reduce_lin(Pa, Pb, Pc, Pd, e2, g, lane);

    if (lane == 0) { wPs[wid] = make_float4(Pa, Pb, Pc, Pd); wEs[wid] = e2; wGs[wid] = g; }
    __syncthreads();
    if (tid == 0) {
        float4 q = wPs[0];
        float Ra = q.x, Rb = q.y, Rc = q.z, Rd = q.w;
        int   re = wEs[0];
        float rg = wGs[0];
        #pragma unroll
        for (int w = 1; w < NWAVE; ++w) {
            float4 t = wPs[w];
            float Ca = Ra*t.x + Rb*t.z;
            float Cb = Ra*t.y + Rb*t.w;
            float Cc = Rc*t.x + Rd*t.z;
            float Cd = Rc*t.y + Rd*t.w;
            Ra = Ca; Rb = Cb; Rc = Cc; Rd = Cd;
            re += wEs[w];
            renorm4(Ra, Rb, Rc, Rd, re);
            rg += wGs[w];
        }
        ((float4*)outP)[blockIdx.x] = make_float4(Ra, Rb, Rc, Rd);
        outE[blockIdx.x] = re;
        outG[blockIdx.x] = rg;
    }
}

__global__ __launch_bounds__(256) void crf_final(
    const float* __restrict__ inP,     // [NBLK,4] mantissas in [1,2)
    const int*   __restrict__ inE,     // [NBLK]
    const float* __restrict__ inG,     // [NBLK]
    float* __restrict__ out)           // [2] = {gold, total} (natural log)
{
    __shared__ float4 wPs[4];
    __shared__ int    wEs[4];
    __shared__ float  wGs[4];

    const int tid  = threadIdx.x;
    const int base = tid * FINAL_PER;

    float4 q = ((const float4*)inP)[base];
    float Pa = q.x, Pb = q.y, Pc = q.z, Pd = q.w;
    int4  ev = ((const int4*)inE)[tid];
    float4 gv = ((const float4*)inG)[tid];
    int   e2 = ev.x + ev.y + ev.z + ev.w;
    float g  = gv.x + gv.y + gv.z + gv.w;
    #pragma unroll
    for (int k = 1; k < FINAL_PER; ++k) {
        float4 r = ((const float4*)inP)[base + k];
        float Ca = Pa*r.x + Pb*r.z;
        float Cb = Pa*r.y + Pb*r.w;
        float Cc = Pc*r.x + Pd*r.z;
        float Cd = Pc*r.y + Pd*r.w;
        Pa = Ca; Pb = Cb; Pc = Cc; Pd = Cd;
    }
    renorm4(Pa, Pb, Pc, Pd, e2);       // growth <= 2^7 over 3 mms of [1,2) inputs

    const int lane = tid & 63;
    wave_reduce_lin(Pa, Pb, Pc, Pd, e2, g, lane);

    const int wid = tid >> 6;
    if (lane == 0) { wPs[wid] = make_float4(Pa, Pb, Pc, Pd); wEs[wid] = e2; wGs[wid] = g; }
    __syncthreads();
    if (tid == 0) {
        float4 q0 = wPs[0];
        float Ra = q0.x, Rb = q0.y, Rc = q0.z, Rd = q0.w;
        int   re = wEs[0];
        float rg = wGs[0];
        #pragma unroll
        for (int w = 1; w < 4; ++w) {
            float4 t = wPs[w];
            float Ca = Ra*t.x + Rb*t.z;
            float Cb = Ra*t.y + Rb*t.w;
            float Cc = Rc*t.x + Rd*t.z;
            float Cd = Rc*t.y + Rd*t.w;
            Ra = Ca; Rb = Cb; Rc = Cc; Rd = Cd;
            re += wEs[w];
            renorm4(Ra, Rb, Rc, Rd, re);
            rg += wGs[w];
        }
        // alpha0 = 0 -> total = log of sum of all 4 entries of the full product.
        out[0] = rg;
        out[1] = ((float)re + flog2(Ra + Rb + Rc + Rd)) * LN2;
    }
}

extern "C" void kernel_launch(void* const* d_in, const int* in_sizes, int n_in,
                              void* d_out, int out_size, void* d_ws, size_t ws_size,
                              hipStream_t stream) {
    const float* em    = (const float*)d_in[0];
    const int*   label = (const int*)  d_in[1];
    const int*   wst   = (const int*)  d_in[2];
    const int*   pst   = (const int*)  d_in[3];
    const float* w2w   = (const float*)d_in[4];
    const float* pos   = (const float*)d_in[5];
    float* out = (float*)d_out;

    float* outP = (float*)d_ws;              // NBLK*4 floats
    int*   outE = (int*)(outP + NBLK * 4);   // NBLK ints
    float* outG = (float*)(outE + NBLK);     // NBLK floats

    crf_partial<<<NBLK, BLOCK, 0, stream>>>(em, label, wst, pst, w2w, pos,
                                            outP, outE, outG);
    crf_final<<<1, 256, 0, stream>>>(outP, outE, outG, out);
}